// Round 11
// baseline (480.771 us; speedup 1.0000x reference)
//
#include <hip/hip_runtime.h>

typedef unsigned short u16;
typedef unsigned int   u32;

#define N_NODES    15000
#define PADN       15008
#define N_EDGES    30000
#define NUM_GRAPHS 600
#define N_STEMS    6000
#define N_JBONDS   3000

#define OUT_FINAL  0
#define OUT_STEM   1200
#define OUT_JB     631200

#define A1S 68                // a1b (global) row stride u16
#define N_CVT 26

// ---- edge-GEMM geometry (v14: dst-owned blocks, atomic-free agg) ----
#define EGRIDE 938            // ceil(30000/32) ownership windows
#define ECAP 48               // max edges per block (32 + maxdeg; Poisson(2) max ~13)
#define KCH 130               // K chunks of 32 (K = 65*64 = 4160)
#define A1LS 66               // a1l row stride u16
#define RS   66               // red row stride f32

// ---- k_node (MFMA) geometry ----
#define NGROUPS (PADN/16)     // 938 groups of 16 nodes
#define NWTILES 28            // root 0-3, wih 4-15, whh 16-27
#define HS 72                 // LDS staging row stride u16

// ---- fused pack kernel segments ----
#define PACK_W2B_N (KCH*2048)        // 266240
#define PACK_NW_N  (NWTILES*4*512)   // 57344
#define PACK_HD_N  1792
#define PACK_TOTAL (PACK_W2B_N + PACK_NW_N + PACK_HD_N)   // 325376 = 1271*256

typedef short frag8 __attribute__((ext_vector_type(8)));   // 8 f16 (4 VGPRs)
typedef float facc4 __attribute__((ext_vector_type(4)));   // 4 f32 acc
typedef _Float16 h16x2 __attribute__((ext_vector_type(2)));

__device__ __forceinline__ float u2f(u16 v){ union{u32 i; float f;} c; c.i=((u32)v)<<16; return c.f; }
__device__ __forceinline__ u16  f2b(float f){ union{float f; u32 u;} c; c.f=f; u32 u=c.u;
                                              return (u16)((u + 0x7fffu + ((u>>16)&1u))>>16); }
__device__ __forceinline__ u16  f2h(float f){ union{_Float16 h; u16 u;} c; c.h = (_Float16)f; return c.u; }
__device__ __forceinline__ float h2f(u16 v){ union{u16 u; _Float16 h;} c; c.u = v; return (float)c.h; }
__device__ __forceinline__ float lrelu(float x){ return x>0.f ? x : 0.01f*x; }
__device__ __forceinline__ float sigmoidf(float x){ return 1.f/(1.f+expf(-x)); }

__device__ __forceinline__ int lower_bound_i(const int* __restrict__ a, int n, int v){
  int lo=0, hi=n;
  while(lo<hi){ int m=(lo+hi)>>1; if(a[m]<v) lo=m+1; else hi=m; }
  return lo;
}

__device__ __forceinline__ void store_out(void* dout, int isf, int idx, float v){
  if(isf) ((float*)dout)[idx] = v;
  else    ((u16*)dout)[idx]   = f2b(v);
}

// fp16 A-fragment: 4x v_pk_mul_f16
__device__ __forceinline__ frag8 pack4h(uint4 v, u32 av2){
  union { u32 d[4]; frag8 f; } au;
  h16x2 a; { union{u32 u; h16x2 h;} c; c.u = av2; a = c.h; }
  { union{u32 u; h16x2 h;} c; c.u = v.x; c.h = a * c.h; au.d[0] = c.u; }
  { union{u32 u; h16x2 h;} c; c.u = v.y; c.h = a * c.h; au.d[1] = c.u; }
  { union{u32 u; h16x2 h;} c; c.u = v.z; c.h = a * c.h; au.d[2] = c.u; }
  { union{u32 u; h16x2 h;} c; c.u = v.w; c.h = a * c.h; au.d[3] = c.u; }
  return au.f;
}

// ---------------- dtype sniff + workspace zero-init ----------------
__global__ __launch_bounds__(256) void k_sniff(const u16* __restrict__ x, int n, int* __restrict__ flag,
                                               float* __restrict__ deg, float* __restrict__ agg,
                                               float* __restrict__ outF, u16* __restrict__ outB,
                                               int* __restrict__ cnt){
  int tid = blockIdx.x*256 + threadIdx.x;
  int stride = gridDim.x*256;
  int local = 0;
  for(int i = tid; i < n; i += stride){
    u16 v = x[i];
    if(((v>>7)&0xFFu) == 0xFFu) local = 1;
  }
  if(local) atomicOr(flag, 1);
  float4 z = (float4){0.f,0.f,0.f,0.f};
  for(int i = tid; i < PADN; i += stride){ deg[i] = 0.f; cnt[i] = 0; }
  for(int i = tid; i < PADN*64/4; i += stride) ((float4*)agg)[i] = z;
  for(int i = tid; i < (PADN-N_NODES)*64/4; i += stride) ((float4*)(outF + (size_t)N_NODES*64))[i] = z;
  for(int i = tid; i < (PADN-N_NODES)*64/8; i += stride) ((float4*)(outB + (size_t)N_NODES*64))[i] = z;
}

// ---------------- convert float inputs to f32 ----------------
struct CvtArgs { const void* src[N_CVT]; float* dst[N_CVT]; int n[N_CVT]; };

__global__ __launch_bounds__(256) void k_cvt(CvtArgs A, const int* __restrict__ flag){
  int isf = *flag;
  int tid = blockIdx.x*256 + threadIdx.x;
  int stride = gridDim.x*256;
  for(int b=0; b<N_CVT; b++){
    int n = A.n[b];
    const float* sf = (const float*)A.src[b];
    const u16*   sb = (const u16*)A.src[b];
    float* d = A.dst[b];
    for(int i=tid; i<n; i+=stride) d[i] = isf ? sf[i] : u2f(sb[i]);
  }
}

// ---------------- lin0 (writes f32 out + fp16 mirror) ----------------
__global__ __launch_bounds__(64) void k_lin0(const float* __restrict__ x, const float* __restrict__ w,
                                             const float* __restrict__ b,
                                             float* __restrict__ outF, u16* __restrict__ outB){
  int n = blockIdx.x, o = threadIdx.x;
  __shared__ float xs[14];
  if(o<14) xs[o] = x[n*14+o];
  __syncthreads();
  float acc = b[o];
  #pragma unroll
  for(int i=0;i<14;i++) acc += xs[i]*w[o*14+i];
  float v = lrelu(acc);
  outF[n*64+o] = v;
  outB[n*64+o] = f2h(v);
}

// ---------------- a1b fp16 (+ deg atomic k==65, int hist k==66) ----------------
__global__ __launch_bounds__(128) void k_a1(const float* __restrict__ ea,
                                            const float* __restrict__ en1w, const float* __restrict__ en1b,
                                            u16* __restrict__ a1b,
                                            const int* __restrict__ ei, float* __restrict__ deg,
                                            int* __restrict__ cnt){
  int e = blockIdx.x, k = threadIdx.x;
  if(k >= A1S) return;
  float v = 0.f;
  if(k < 64){
    float acc = en1b[k];
    #pragma unroll
    for(int c=0;c<4;c++) acc += ea[e*4+c] * en1w[k*4+c];
    v = lrelu(acc);
  } else if(k == 64) v = 1.0f;
  a1b[e*A1S + k] = f2h(v);
  if(k == 65) atomicAdd(&deg[ei[N_EDGES + e]], 1.0f);
  if(k == 66) atomicAdd(&cnt[ei[N_EDGES + e]], 1);
}

// ---------------- exclusive prefix scan of cnt -> start, cursor (one block) ----------------
__global__ __launch_bounds__(1024) void k_scan(const int* __restrict__ cnt,
                                               int* __restrict__ startA, int* __restrict__ cursor){
  __shared__ int part[1024];
  int th = threadIdx.x;
  int base = th*15;                         // 15*1024 = 15360 >= PADN
  int loc[15];
  int s = 0;
  #pragma unroll
  for(int i=0;i<15;i++){
    int idx = base+i;
    int v = (idx < PADN) ? cnt[idx] : 0;
    loc[i] = s; s += v;
  }
  part[th] = s;
  __syncthreads();
  for(int off=1; off<1024; off<<=1){
    int v = part[th];
    int u = (th >= off) ? part[th-off] : 0;
    __syncthreads();
    part[th] = v + u;
    __syncthreads();
  }
  int pre = (th==0) ? 0 : part[th-1];
  #pragma unroll
  for(int i=0;i<15;i++){
    int idx = base+i;
    if(idx < PADN){ int v = pre + loc[i]; startA[idx] = v; cursor[idx] = v; }
  }
}

// ---------------- scatter edges into dst-sorted order ----------------
__global__ __launch_bounds__(256) void k_scatter(const int* __restrict__ ei, int* __restrict__ cursor,
                                                 int* __restrict__ sidx, int* __restrict__ sdst){
  int e = blockIdx.x*256 + threadIdx.x;
  if(e < N_EDGES){
    int d = ei[N_EDGES + e];
    int pos = atomicAdd(&cursor[d], 1);
    sidx[pos] = e; sdst[pos] = d;
  }
}

// ---------------- fused weight-pack kernel (W2b + NodeW + Heads), fp16 ----------------
__global__ __launch_bounds__(256) void k_packAll(const float* __restrict__ en2w, const float* __restrict__ en2b,
                                                 u16* __restrict__ B2b,
                                                 const float* __restrict__ rootw, const float* __restrict__ wih,
                                                 const float* __restrict__ whh, u16* __restrict__ gBn,
                                                 const float* __restrict__ s1w, const float* __restrict__ s2w,
                                                 const float* __restrict__ j1w,
                                                 float4* __restrict__ s1P, float4* __restrict__ s2P,
                                                 float4* __restrict__ j1P){
  int idx = blockIdx.x*256 + threadIdx.x;
  if(idx < PACK_W2B_N){
    int jj  = idx & 7;
    int l   = (idx >> 3) & 63;
    int nt  = (idx >> 9) & 3;
    int c   = idx >> 11;
    int q = l >> 4, m16 = l & 15;
    int kidx = c*32 + q*8 + jj;
    int k = kidx >> 6, j = kidx & 63;
    int o = nt*16 + m16;
    float v = (k < 64) ? en2w[((size_t)(j*64 + o))*64 + k] : en2b[j*64 + o];
    B2b[idx] = f2h(v);
    return;
  }
  idx -= PACK_W2B_N;
  if(idx < PACK_NW_N){
    int jj = idx & 7, l = (idx>>3) & 63, ch = (idx>>9) & 3, t = idx >> 11;
    int m16 = l & 15, q = l >> 4;
    int j = ((ch & 1) ? 32 : 0) + q*8 + jj;
    float v;
    if(t < 4){        int o = t*16 + m16;        v = rootw[j*64 + o]; }
    else if(t < 16){  int g = (t-4)*16 + m16;    v = wih[(size_t)g*64 + j]; }
    else {            int g = (t-16)*16 + m16;   v = whh[(size_t)g*64 + j]; }
    u16 hb = f2h(v);
    gBn[idx] = (ch >> 1) ? f2h(v - h2f(hb)) : hb;
    return;
  }
  idx -= PACK_NW_N;
  if(idx < PACK_HD_N){
    if(idx < 1024){
      int o = idx & 63, j4 = idx >> 6;
      const float* r = s1w + o*64 + 4*j4;
      s1P[idx] = (float4){r[0], r[1], r[2], r[3]};
      const float* r2 = j1w + o*64 + 4*j4;
      j1P[idx] = (float4){r2[0], r2[1], r2[2], r2[3]};
    }
    {
      int j4 = idx / 112, t = idx % 112;
      float4 v = {0.f,0.f,0.f,0.f};
      if(t < 105){
        const float* r = s2w + t*64 + 4*j4;
        v = (float4){r[0], r[1], r[2], r[3]};
      }
      s2P[idx] = v;
    }
  }
}

// ---------------- edge-GEMM v14: dst-owned blocks, atomic-free agg ----------------
// R10 post-mortem: 3rd consecutive null (VALU x7 cut neutral; occupancy, prefetch neutral
// before). Resource arithmetic can't explain 37.5us -> unmodeled binder = the 1.92M
// device-scope atomicAdds to agg at random dst (avg deg 2 -> nearly every agg line
// atomically hit by ~2 blocks on DIFFERENT XCDs -> per-line coherence migration; R8 showed
// the violent version). v14: edges counting-sorted by dst (static across iters); block b
// owns dsts {d: start[d] in [32b,32b+32)}; processes all their edges (<=48, 2-3 tiles);
// agg written with PLAIN STORES - zero atomics, zero cross-block line sharing.
template<int NT>
__device__ __forceinline__ void egemm_core(int l, int w, int m16, int q, int n,
                                           const u16* __restrict__ outB,
                                           const frag8* __restrict__ Bg,
                                           const u16* a1l, const int* srcL, float* red){
  uint4 oE[NT], oO[NT];
  #pragma unroll
  for(int t=0;t<NT;t++){
    int node = srcL[t*16 + m16];
    oE[t] = *(const uint4*)(outB + (size_t)node*64 +      q*8);
    oO[t] = *(const uint4*)(outB + (size_t)node*64 + 32 + q*8);
  }

  facc4 acc[NT][4];
  #pragma unroll
  for(int t=0;t<NT;t++)
    #pragma unroll
    for(int nt=0;nt<4;nt++) acc[t][nt] = (facc4){0.f,0.f,0.f,0.f};

  int ks = (w*65) >> 3, ke = ((w+1)*65) >> 3;   // 8 waves over 65 pairs

  frag8 bA[4], bB[4];
  #pragma unroll
  for(int nt=0;nt<4;nt++) bA[nt] = Bg[(size_t)(2*ks)*256 + nt*64 + l];

  for(int k = ks; k < ke; ++k){
    #pragma unroll
    for(int nt=0;nt<4;nt++) bB[nt] = Bg[(size_t)(2*k+1)*256 + nt*64 + l];

    u32 av[NT];
    #pragma unroll
    for(int t=0;t<NT;t++){
      u32 a = a1l[(t*16 + m16)*A1LS + k];
      av[t] = a | (a << 16);
    }

    #pragma unroll
    for(int t=0;t<NT;t++){
      frag8 a = pack4h(oE[t], av[t]);
      #pragma unroll
      for(int nt=0;nt<4;nt++)
        acc[t][nt] = __builtin_amdgcn_mfma_f32_16x16x32_f16(a, bA[nt], acc[t][nt], 0,0,0);
    }

    int kn = (k+1 < ke) ? (k+1) : k;
    #pragma unroll
    for(int nt=0;nt<4;nt++) bA[nt] = Bg[(size_t)(2*kn)*256 + nt*64 + l];

    #pragma unroll
    for(int t=0;t<NT;t++){
      frag8 a = pack4h(oO[t], av[t]);
      #pragma unroll
      for(int nt=0;nt<4;nt++)
        acc[t][nt] = __builtin_amdgcn_mfma_f32_16x16x32_f16(a, bB[nt], acc[t][nt], 0,0,0);
    }
  }

  // reduce: waves 0-3 exclusive-write slab w; waves 4-7 += into slab w-4
  float* slab = red + (size_t)((w < 4) ? w : (w-4)) * (ECAP*RS);
  if(w < 4){
    #pragma unroll
    for(int t=0;t<NT;t++)
      #pragma unroll
      for(int nt=0;nt<4;nt++)
        #pragma unroll
        for(int r=0;r<4;r++){
          int el = t*16 + q*4 + r;
          slab[el*RS + nt*16 + m16] = acc[t][nt][r];
        }
  }
  __syncthreads();
  if(w >= 4){
    #pragma unroll
    for(int t=0;t<NT;t++)
      #pragma unroll
      for(int nt=0;nt<4;nt++)
        #pragma unroll
        for(int r=0;r<4;r++){
          int el = t*16 + q*4 + r;
          slab[el*RS + nt*16 + m16] += acc[t][nt][r];
        }
  }
  __syncthreads();
}

__global__ __launch_bounds__(512, 2) void k_egemm(const u16* __restrict__ outB,
                                               const u16* __restrict__ a1b,
                                               const u16* __restrict__ B2b,
                                               const int* __restrict__ ei,
                                               const int* __restrict__ sidx,
                                               const int* __restrict__ sdst,
                                               float* __restrict__ agg){
  int tid = threadIdx.x;
  int l = tid & 63, w = tid >> 6;          // w in 0..7
  int m16 = l & 15, q = l >> 4;
  int w32 = blockIdx.x * 32;

  __shared__ __align__(16) u16 a1l[ECAP*A1LS];        // 6336 B
  __shared__ __align__(16) float red[4*ECAP*RS];      // 50688 B
  __shared__ int sdstW[52];
  __shared__ int srcL[ECAP];

  // stage dst window: sdstW[i] = sdst[w32-1+i]; sentinels -1 (before), -2 (past end)
  for(int i = tid; i < 52; i += 512){
    int j = w32 - 1 + i;
    sdstW[i] = (j < 0) ? -1 : ((j < N_EDGES) ? sdst[j] : -2);
  }
  __syncthreads();

  // ownership bounds (uniform across block, from LDS)
  int li = 1;
  while(li < 52 && sdstW[li] == sdstW[li-1]) li++;
  int hiI = 33;
  while(hiI < 52 && sdstW[hiI] == sdstW[hiI-1]) hiI++;
  int lo = w32 - 1 + li;
  int hi = w32 - 1 + hiI; if(hi > N_EDGES) hi = N_EDGES;
  int n = hi - lo; if(n < 0) n = 0; if(n > ECAP) n = ECAP;

  // stage source nodes + a1 rows for owned edges
  for(int el = tid; el < ECAP; el += 512)
    srcL[el] = (el < n) ? ei[sidx[lo + el]] : 0;
  for(int idx = tid; idx < ECAP*33; idx += 512){
    int r = idx / 33, c = idx - r*33;
    u32 v = 0;
    if(r < n){
      int orig = sidx[lo + r];
      v = ((const u32*)(a1b + (size_t)orig*A1S))[c];
    }
    ((u32*)a1l)[r*33 + c] = v;
  }
  __syncthreads();

  const frag8* __restrict__ Bg = (const frag8*)B2b;
  if(n <= 32) egemm_core<2>(l, w, m16, q, n, outB, Bg, a1l, srcL, red);
  else        egemm_core<3>(l, w, m16, q, n, outB, Bg, a1l, srcL, red);

  // segmented sum + PLAIN STORE (each dst owned by exactly this block)
  for(int i = tid; i < n*64; i += 512){
    int el = i >> 6, o = i & 63;
    int d = sdstW[li + el];
    bool first = (el == 0) || (sdstW[li + el - 1] != d);
    if(first){
      float s = 0.f;
      int e2 = el;
      while(e2 < n && sdstW[li + e2] == d){
        s += red[0*ECAP*RS + e2*RS + o] + red[1*ECAP*RS + e2*RS + o]
           + red[2*ECAP*RS + e2*RS + o] + red[3*ECAP*RS + e2*RS + o];
        e2++;
      }
      agg[(size_t)d*64 + o] = s;
    }
  }
}

// ---------------- node update: MFMA GRU, fp16 split datapath (unchanged) ----------------
__global__ __launch_bounds__(256) void k_node(float* __restrict__ agg, const float* __restrict__ deg,
                                              float* __restrict__ outF, u16* __restrict__ outB,
                                              const u16* __restrict__ gBn, const float* __restrict__ convb,
                                              const float* __restrict__ bih, const float* __restrict__ bhh){
  int tid = threadIdx.x;
  int l = tid & 63, w = tid >> 6;
  int m16 = l & 15, q = l >> 4;
  int nb = blockIdx.x * 16;

  __shared__ __align__(16) u16 hhi[16][HS], hlo[16][HS];
  __shared__ __align__(16) u16 mhi[16][HS], mlo[16][HS];

  {
    float4 v = ((const float4*)(outF + (size_t)nb*64))[tid];
    int base = tid*4;
    int node = base >> 6, o = base & 63;
    float vv[4] = {v.x, v.y, v.z, v.w};
    #pragma unroll
    for(int t=0;t<4;t++){
      u16 hb = f2h(vv[t]);
      hhi[node][o+t] = hb;
      hlo[node][o+t] = f2h(vv[t] - h2f(hb));
    }
  }
  __syncthreads();

  const frag8* __restrict__ Bg = (const frag8*)gBn;

#define GEMM6(ACC, A0, A1, L0, L1, T)                                      \
  {                                                                        \
    const frag8* bp = Bg + (size_t)(T)*256 + l;                            \
    frag8 b0 = bp[0], b1 = bp[64], b2 = bp[128], b3 = bp[192];             \
    ACC = __builtin_amdgcn_mfma_f32_16x16x32_f16(A0, b0, ACC, 0,0,0);      \
    ACC = __builtin_amdgcn_mfma_f32_16x16x32_f16(A1, b1, ACC, 0,0,0);      \
    ACC = __builtin_amdgcn_mfma_f32_16x16x32_f16(L0, b0, ACC, 0,0,0);      \
    ACC = __builtin_amdgcn_mfma_f32_16x16x32_f16(L1, b1, ACC, 0,0,0);      \
    ACC = __builtin_amdgcn_mfma_f32_16x16x32_f16(A0, b2, ACC, 0,0,0);      \
    ACC = __builtin_amdgcn_mfma_f32_16x16x32_f16(A1, b3, ACC, 0,0,0);      \
  }

  frag8 hA0 = *(const frag8*)&hhi[m16][q*8];
  frag8 hA1 = *(const frag8*)&hhi[m16][32 + q*8];
  frag8 hL0 = *(const frag8*)&hlo[m16][q*8];
  frag8 hL1 = *(const frag8*)&hlo[m16][32 + q*8];

  facc4 dR  = (facc4){0.f,0.f,0.f,0.f};
  facc4 ghA = (facc4){0.f,0.f,0.f,0.f};
  facc4 ghB = (facc4){0.f,0.f,0.f,0.f};
  facc4 ghC = (facc4){0.f,0.f,0.f,0.f};
  GEMM6(dR,  hA0, hA1, hL0, hL1, w);
  GEMM6(ghA, hA0, hA1, hL0, hL1, 16 + w);
  GEMM6(ghB, hA0, hA1, hL0, hL1, 20 + w);
  GEMM6(ghC, hA0, hA1, hL0, hL1, 24 + w);

  int o = w*16 + m16;
  float cb = convb[o];
  #pragma unroll
  for(int r=0;r<4;r++){
    int node = q*4 + r;
    int n = nb + node;
    float a = agg[(size_t)n*64 + o] / fmaxf(deg[n], 1.0f) + dR[r] + cb;
    agg[(size_t)n*64 + o] = 0.f;
    float mv = lrelu(a);
    u16 mb = f2h(mv);
    mhi[node][o] = mb;
    mlo[node][o] = f2h(mv - h2f(mb));
  }
  __syncthreads();

  frag8 mA0 = *(const frag8*)&mhi[m16][q*8];
  frag8 mA1 = *(const frag8*)&mhi[m16][32 + q*8];
  frag8 mL0 = *(const frag8*)&mlo[m16][q*8];
  frag8 mL1 = *(const frag8*)&mlo[m16][32 + q*8];

  facc4 giA = (facc4){0.f,0.f,0.f,0.f};
  facc4 giB = (facc4){0.f,0.f,0.f,0.f};
  facc4 giC = (facc4){0.f,0.f,0.f,0.f};
  GEMM6(giA, mA0, mA1, mL0, mL1, 4 + w);
  GEMM6(giB, mA0, mA1, mL0, mL1, 8 + w);
  GEMM6(giC, mA0, mA1, mL0, mL1, 12 + w);
#undef GEMM6

  float bi0 = bih[o], bi1 = bih[64+o], bi2 = bih[128+o];
  float bh0 = bhh[o], bh1 = bhh[64+o], bh2 = bhh[128+o];
  #pragma unroll
  for(int r=0;r<4;r++){
    int node = q*4 + r;
    int n = nb + node;
    float ir = giA[r]+bi0, iz = giB[r]+bi1, inn = giC[r]+bi2;
    float hr = ghA[r]+bh0, hz = ghB[r]+bh1, hn = ghC[r]+bh2;
    float rr  = sigmoidf(ir + hr);
    float z   = sigmoidf(iz + hz);
    float ngv = tanhf(inn + rr*hn);
    float hold = h2f(hhi[node][o]) + h2f(hlo[node][o]);
    float hnew = (1.f - z)*ngv + z*hold;
    if(n < N_NODES){
      outF[(size_t)n*64 + o] = hnew;
      outB[(size_t)n*64 + o] = f2h(hnew);
    }
  }
}

// ---------------- stem head ----------------
__global__ __launch_bounds__(512) void k_stem(const float* __restrict__ outF, const int* __restrict__ sidx,
                                              const float4* __restrict__ s1P, const float* __restrict__ s1b,
                                              const float4* __restrict__ s2P, const float* __restrict__ s2b,
                                              void* __restrict__ dout, const int* __restrict__ flag){
  int grp = threadIdx.x >> 7, t = threadIdx.x & 127;
  int s = blockIdx.x*4 + grp;
  int isf = *flag;
  __shared__ __align__(16) float xs[4][64], hid[4][64];
  int a = sidx[s];
  if(t < 64) xs[grp][t] = outF[(size_t)a*64 + t];
  __syncthreads();
  if(t < 64){
    float acc = s1b[t];
    const float4* xp = (const float4*)xs[grp];
    #pragma unroll 8
    for(int j4=0;j4<16;j4++){
      float4 w = s1P[j4*64+t];
      float4 x = xp[j4];
      acc += w.x*x.x + w.y*x.y + w.z*x.z + w.w*x.w;
    }
    hid[grp][t] = lrelu(acc);
  }
  __syncthreads();
  if(t < 105){
    float acc = s2b[t];
    const float4* hp = (const float4*)hid[grp];
    #pragma unroll 8
    for(int j4=0;j4<16;j4++){
      float4 w = s2P[j4*112+t];
      float4 h = hp[j4];
      acc += w.x*h.x + w.y*h.y + w.z*h.z + w.w*h.w;
    }
    store_out(dout, isf, OUT_STEM + s*105 + t, acc);
  }
}

// ---------------- jbond head ----------------
__global__ __launch_bounds__(512) void k_jbond(const float* __restrict__ outF, const int* __restrict__ jidx,
                                               const float4* __restrict__ j1P, const float* __restrict__ j1b,
                                               const float* __restrict__ j2w, const float* __restrict__ j2b,
                                               void* __restrict__ dout, const int* __restrict__ flag){
  int grp = threadIdx.x >> 7, t = threadIdx.x & 127;
  int jb = blockIdx.x*4 + grp;
  int isf = *flag;
  __shared__ __align__(16) float xs[4][2][64], hid[4][2][64];
  int at = t >> 6, k = t & 63;
  int a = jidx[jb*2 + at];
  xs[grp][at][k] = outF[(size_t)a*64 + k];
  __syncthreads();
  {
    float acc = j1b[k];
    const float4* xp = (const float4*)xs[grp][at];
    #pragma unroll 8
    for(int j4=0;j4<16;j4++){
      float4 w = j1P[j4*64+k];
      float4 x = xp[j4];
      acc += w.x*x.x + w.y*x.y + w.z*x.z + w.w*x.w;
    }
    hid[grp][at][k] = lrelu(acc);
  }
  __syncthreads();
  if(t < 64){
    float p = (hid[grp][0][t] + hid[grp][1][t]) * j2w[t];
    #pragma unroll
    for(int s=32;s;s>>=1) p += __shfl_xor(p, s, 64);
    if(t==0) store_out(dout, isf, OUT_JB + jb, 0.5f*p + j2b[0]);
  }
}

// ---------------- Set2Set + final linear ----------------
__global__ __launch_bounds__(64) void k_s2s(const float* __restrict__ outF, const int* __restrict__ batch,
                                            const float* __restrict__ bih, const float* __restrict__ bhh,
                                            const float* __restrict__ loutw, const float* __restrict__ loutb,
                                            void* __restrict__ dout, const int* __restrict__ flag){
  int b = blockIdx.x, t = threadIdx.x;
  int isf = *flag;
  float i_ = bih[t]     + bhh[t];
  float g_ = bih[128+t] + bhh[128+t];
  float o_ = bih[192+t] + bhh[192+t];
  float c  = sigmoidf(i_)*tanhf(g_);
  float q  = sigmoidf(o_)*tanhf(c);

  int lo = lower_bound_i(batch, N_NODES, b);
  int hi = lower_bound_i(batch, N_NODES, b+1);

  float emax = -3.4e38f;
  for(int n=lo;n<hi;n++){
    float p = outF[n*64+t]*q;
    #pragma unroll
    for(int s=32;s;s>>=1) p += __shfl_xor(p, s, 64);
    emax = fmaxf(emax, p);
  }
  float Z = 0.f, racc = 0.f;
  for(int n=lo;n<hi;n++){
    float v = outF[n*64+t];
    float p = v*q;
    #pragma unroll
    for(int s=32;s;s>>=1) p += __shfl_xor(p, s, 64);
    float w = expf(p - emax);
    Z += w; racc += w*v;
  }
  float rp = (hi>lo) ? racc/Z : 0.f;

  #pragma unroll
  for(int j=0;j<2;j++){
    float p = q*loutw[j*128+t] + rp*loutw[j*128+64+t];
    #pragma unroll
    for(int s=32;s;s>>=1) p += __shfl_xor(p, s, 64);
    if(t==0) store_out(dout, isf, OUT_FINAL + b*2 + j, p + loutb[j]);
  }
}

extern "C" void kernel_launch(void* const* d_in, const int* in_sizes, int n_in,
                              void* d_out, int out_size, void* d_ws, size_t ws_size,
                              hipStream_t stream) {
  const int* edge_index  = (const int*)d_in[28];
  const int* stem_atmidx = (const int*)d_in[29];
  const int* jbond_atmidx= (const int*)d_in[30];
  const int* batch       = (const int*)d_in[31];

  char* ws = (char*)d_ws;
  size_t off = 0;
  auto alloc = [&](size_t bytes)->void*{ void* p = ws + off; off = (off + bytes + 255) & ~(size_t)255; return p; };

  int*   flag = (int*)  alloc(4);
  float* outF = (float*)alloc((size_t)PADN*64*4);
  u16*   outB = (u16*)  alloc((size_t)PADN*64*2);
  float* agg  = (float*)alloc((size_t)PADN*64*4);
  u16*   a1b  = (u16*)  alloc((size_t)N_EDGES*A1S*2);
  u16*   B2b  = (u16*)  alloc((size_t)KCH*2048*2 + 2048*2);   // +1 chunk slack for prefetch tail
  u16*   gBn  = (u16*)  alloc((size_t)NWTILES*4*512*2);       // node-GEMM weights (112 KB)
  float* deg  = (float*)alloc((size_t)PADN*4);
  int*   cnt    = (int*)alloc((size_t)PADN*4);
  int*   startA = (int*)alloc((size_t)PADN*4);
  int*   cursor = (int*)alloc((size_t)PADN*4);
  int*   sidx   = (int*)alloc((size_t)N_EDGES*4);
  int*   sdst   = (int*)alloc((size_t)N_EDGES*4);
  float4* s1P   = (float4*)alloc(1024*16);
  float4* s2P   = (float4*)alloc(1792*16);
  float4* j1P   = (float4*)alloc(1024*16);

  static const int cvt_idx[N_CVT] = {0,1,2,3,4,5,6,7,8,9,10,11,12,13,14,15,16,17,18,19,20,21,24,25,26,27};
  CvtArgs A;
  float* cF[N_CVT];
  for(int i=0;i<N_CVT;i++){
    int src = cvt_idx[i];
    int n = in_sizes[src];
    cF[i] = (float*)alloc((size_t)n*4);
    A.src[i] = d_in[src];
    A.dst[i] = cF[i];
    A.n[i]   = n;
  }
  (void)ws_size; (void)n_in; (void)out_size;
  float* xF=cF[0];   float* eaF=cF[1];  float* l0w=cF[2];  float* l0b=cF[3];
  float* e1w=cF[4];  float* e1b=cF[5];  float* e2w=cF[6];  float* e2b=cF[7];
  float* rootw=cF[8];float* convb=cF[9];
  float* wih=cF[10]; float* whh=cF[11]; float* bih=cF[12]; float* bhh=cF[13];
  float* s1w=cF[14]; float* s1b=cF[15]; float* s2w=cF[16]; float* s2b=cF[17];
  float* j1w=cF[18]; float* j1b=cF[19]; float* j2w=cF[20]; float* j2b=cF[21];
  float* lbih=cF[22];float* lbhh=cF[23];float* loutw=cF[24];float* loutb=cF[25];

  hipMemsetAsync(flag, 0, 4, stream);

  k_sniff <<<128, 256, 0, stream>>>((const u16*)d_in[0], in_sizes[0], flag, deg, agg, outF, outB, cnt);
  k_cvt   <<<512, 256, 0, stream>>>(A, flag);

  k_lin0    <<<N_NODES, 64, 0, stream>>>(xF, l0w, l0b, outF, outB);
  k_a1      <<<N_EDGES, 128, 0, stream>>>(eaF, e1w, e1b, a1b, edge_index, deg, cnt);
  k_packAll <<<PACK_TOTAL/256, 256, 0, stream>>>(e2w, e2b, B2b, rootw, wih, whh, gBn,
                                                 s1w, s2w, j1w, s1P, s2P, j1P);
  k_scan    <<<1, 1024, 0, stream>>>(cnt, startA, cursor);
  k_scatter <<<(N_EDGES+255)/256, 256, 0, stream>>>(edge_index, cursor, sidx, sdst);

  for(int it=0; it<6; it++){
    k_egemm<<<EGRIDE, 512, 0, stream>>>(outB, a1b, B2b, edge_index, sidx, sdst, agg);
    k_node <<<NGROUPS, 256, 0, stream>>>(agg, deg, outF, outB, gBn, convb, bih, bhh);
  }

  k_stem <<<N_STEMS/4, 512, 0, stream>>>(outF, stem_atmidx, s1P, s1b, s2P, s2b, d_out, flag);
  k_jbond<<<N_JBONDS/4, 512, 0, stream>>>(outF, jbond_atmidx, j1P, j1b, j2w, j2b, d_out, flag);
  k_s2s  <<<NUM_GRAPHS, 64, 0, stream>>>(outF, batch, lbih, lbhh, loutw, loutb, d_out, flag);
}

// Round 12
// 436.947 us; speedup vs baseline: 1.1003x; 1.1003x over previous
//
#include <hip/hip_runtime.h>

typedef unsigned short u16;
typedef unsigned int   u32;

#define N_NODES    15000
#define PADN       15008
#define N_EDGES    30000
#define NUM_GRAPHS 600
#define N_STEMS    6000
#define N_JBONDS   3000

#define OUT_FINAL  0
#define OUT_STEM   1200
#define OUT_JB     631200

#define A1S 68                // a1b (global) row stride u16
#define N_CVT 26

// ---- edge-GEMM geometry (v15: EBLK=64, 8 waves, full-K, single-block atomics) ----
#define EBLK 64               // edges per block (4 MFMA tiles)
#define EGRIDE 469            // ceil(30000/64)
#define KCH 130               // K chunks of 32 (K = 65*64 = 4160)
#define A1LS 66               // a1l row stride u16
#define RS   66               // red row stride f32

// ---- k_node (MFMA) geometry ----
#define NGROUPS (PADN/16)     // 938 groups of 16 nodes
#define NWTILES 28            // root 0-3, wih 4-15, whh 16-27
#define HS 72                 // LDS staging row stride u16

// ---- fused pack kernel segments ----
#define PACK_W2B_N (KCH*2048)        // 266240
#define PACK_NW_N  (NWTILES*4*512)   // 57344
#define PACK_HD_N  1792
#define PACK_TOTAL (PACK_W2B_N + PACK_NW_N + PACK_HD_N)   // 325376 = 1271*256

typedef short frag8 __attribute__((ext_vector_type(8)));   // 8 f16 (4 VGPRs)
typedef float facc4 __attribute__((ext_vector_type(4)));   // 4 f32 acc
typedef _Float16 h16x2 __attribute__((ext_vector_type(2)));

__device__ __forceinline__ float u2f(u16 v){ union{u32 i; float f;} c; c.i=((u32)v)<<16; return c.f; }
__device__ __forceinline__ u16  f2b(float f){ union{float f; u32 u;} c; c.f=f; u32 u=c.u;
                                              return (u16)((u + 0x7fffu + ((u>>16)&1u))>>16); }
__device__ __forceinline__ u16  f2h(float f){ union{_Float16 h; u16 u;} c; c.h = (_Float16)f; return c.u; }
__device__ __forceinline__ float h2f(u16 v){ union{u16 u; _Float16 h;} c; c.u = v; return (float)c.h; }
__device__ __forceinline__ float lrelu(float x){ return x>0.f ? x : 0.01f*x; }
__device__ __forceinline__ float sigmoidf(float x){ return 1.f/(1.f+expf(-x)); }

__device__ __forceinline__ int lower_bound_i(const int* __restrict__ a, int n, int v){
  int lo=0, hi=n;
  while(lo<hi){ int m=(lo+hi)>>1; if(a[m]<v) lo=m+1; else hi=m; }
  return lo;
}

__device__ __forceinline__ void store_out(void* dout, int isf, int idx, float v){
  if(isf) ((float*)dout)[idx] = v;
  else    ((u16*)dout)[idx]   = f2b(v);
}

// fp16 A-fragment: 4x v_pk_mul_f16
__device__ __forceinline__ frag8 pack4h(uint4 v, u32 av2){
  union { u32 d[4]; frag8 f; } au;
  h16x2 a; { union{u32 u; h16x2 h;} c; c.u = av2; a = c.h; }
  { union{u32 u; h16x2 h;} c; c.u = v.x; c.h = a * c.h; au.d[0] = c.u; }
  { union{u32 u; h16x2 h;} c; c.u = v.y; c.h = a * c.h; au.d[1] = c.u; }
  { union{u32 u; h16x2 h;} c; c.u = v.z; c.h = a * c.h; au.d[2] = c.u; }
  { union{u32 u; h16x2 h;} c; c.u = v.w; c.h = a * c.h; au.d[3] = c.u; }
  return au.f;
}

// ---------------- dtype sniff + workspace zero-init ----------------
__global__ __launch_bounds__(256) void k_sniff(const u16* __restrict__ x, int n, int* __restrict__ flag,
                                               float* __restrict__ deg, float* __restrict__ agg,
                                               float* __restrict__ outF, u16* __restrict__ outB){
  int tid = blockIdx.x*256 + threadIdx.x;
  int stride = gridDim.x*256;
  int local = 0;
  for(int i = tid; i < n; i += stride){
    u16 v = x[i];
    if(((v>>7)&0xFFu) == 0xFFu) local = 1;
  }
  if(local) atomicOr(flag, 1);
  float4 z = (float4){0.f,0.f,0.f,0.f};
  for(int i = tid; i < PADN; i += stride) deg[i] = 0.f;
  for(int i = tid; i < PADN*64/4; i += stride) ((float4*)agg)[i] = z;
  for(int i = tid; i < (PADN-N_NODES)*64/4; i += stride) ((float4*)(outF + (size_t)N_NODES*64))[i] = z;
  for(int i = tid; i < (PADN-N_NODES)*64/8; i += stride) ((float4*)(outB + (size_t)N_NODES*64))[i] = z;
}

// ---------------- convert float inputs to f32 ----------------
struct CvtArgs { const void* src[N_CVT]; float* dst[N_CVT]; int n[N_CVT]; };

__global__ __launch_bounds__(256) void k_cvt(CvtArgs A, const int* __restrict__ flag){
  int isf = *flag;
  int tid = blockIdx.x*256 + threadIdx.x;
  int stride = gridDim.x*256;
  for(int b=0; b<N_CVT; b++){
    int n = A.n[b];
    const float* sf = (const float*)A.src[b];
    const u16*   sb = (const u16*)A.src[b];
    float* d = A.dst[b];
    for(int i=tid; i<n; i+=stride) d[i] = isf ? sf[i] : u2f(sb[i]);
  }
}

// ---------------- lin0 (writes f32 out + fp16 mirror) ----------------
__global__ __launch_bounds__(64) void k_lin0(const float* __restrict__ x, const float* __restrict__ w,
                                             const float* __restrict__ b,
                                             float* __restrict__ outF, u16* __restrict__ outB){
  int n = blockIdx.x, o = threadIdx.x;
  __shared__ float xs[14];
  if(o<14) xs[o] = x[n*14+o];
  __syncthreads();
  float acc = b[o];
  #pragma unroll
  for(int i=0;i<14;i++) acc += xs[i]*w[o*14+i];
  float v = lrelu(acc);
  outF[n*64+o] = v;
  outB[n*64+o] = f2h(v);
}

// ---------------- a1b fp16 (+ folded deg atomic on thread k==65) ----------------
__global__ __launch_bounds__(128) void k_a1(const float* __restrict__ ea,
                                            const float* __restrict__ en1w, const float* __restrict__ en1b,
                                            u16* __restrict__ a1b,
                                            const int* __restrict__ ei, float* __restrict__ deg){
  int e = blockIdx.x, k = threadIdx.x;
  if(k >= A1S) return;
  float v = 0.f;
  if(k < 64){
    float acc = en1b[k];
    #pragma unroll
    for(int c=0;c<4;c++) acc += ea[e*4+c] * en1w[k*4+c];
    v = lrelu(acc);
  } else if(k == 64) v = 1.0f;
  a1b[e*A1S + k] = f2h(v);
  if(k == 65) atomicAdd(&deg[ei[N_EDGES + e]], 1.0f);
}

// ---------------- fused weight-pack kernel (W2b + NodeW + Heads), fp16 ----------------
__global__ __launch_bounds__(256) void k_packAll(const float* __restrict__ en2w, const float* __restrict__ en2b,
                                                 u16* __restrict__ B2b,
                                                 const float* __restrict__ rootw, const float* __restrict__ wih,
                                                 const float* __restrict__ whh, u16* __restrict__ gBn,
                                                 const float* __restrict__ s1w, const float* __restrict__ s2w,
                                                 const float* __restrict__ j1w,
                                                 float4* __restrict__ s1P, float4* __restrict__ s2P,
                                                 float4* __restrict__ j1P){
  int idx = blockIdx.x*256 + threadIdx.x;
  if(idx < PACK_W2B_N){
    int jj  = idx & 7;
    int l   = (idx >> 3) & 63;
    int nt  = (idx >> 9) & 3;
    int c   = idx >> 11;
    int q = l >> 4, m16 = l & 15;
    int kidx = c*32 + q*8 + jj;
    int k = kidx >> 6, j = kidx & 63;
    int o = nt*16 + m16;
    float v = (k < 64) ? en2w[((size_t)(j*64 + o))*64 + k] : en2b[j*64 + o];
    B2b[idx] = f2h(v);
    return;
  }
  idx -= PACK_W2B_N;
  if(idx < PACK_NW_N){
    int jj = idx & 7, l = (idx>>3) & 63, ch = (idx>>9) & 3, t = idx >> 11;
    int m16 = l & 15, q = l >> 4;
    int j = ((ch & 1) ? 32 : 0) + q*8 + jj;
    float v;
    if(t < 4){        int o = t*16 + m16;        v = rootw[j*64 + o]; }
    else if(t < 16){  int g = (t-4)*16 + m16;    v = wih[(size_t)g*64 + j]; }
    else {            int g = (t-16)*16 + m16;   v = whh[(size_t)g*64 + j]; }
    u16 hb = f2h(v);
    gBn[idx] = (ch >> 1) ? f2h(v - h2f(hb)) : hb;
    return;
  }
  idx -= PACK_NW_N;
  if(idx < PACK_HD_N){
    if(idx < 1024){
      int o = idx & 63, j4 = idx >> 6;
      const float* r = s1w + o*64 + 4*j4;
      s1P[idx] = (float4){r[0], r[1], r[2], r[3]};
      const float* r2 = j1w + o*64 + 4*j4;
      j1P[idx] = (float4){r2[0], r2[1], r2[2], r2[3]};
    }
    {
      int j4 = idx / 112, t = idx % 112;
      float4 v = {0.f,0.f,0.f,0.f};
      if(t < 105){
        const float* r = s2w + t*64 + 4*j4;
        v = (float4){r[0], r[1], r[2], r[3]};
      }
      s2P[idx] = v;
    }
  }
}

// ---------------- edge-GEMM v15: EBLK=64, 512 threads, full-K, single-block atomics ----------------
// R11 post-mortem: atomic-free dst-ownership NEUTRAL-to-worse -> atomics exonerated. Unified
// model fitting ALL rounds: k_egemm = B-bytes / ~13 TB/s effective aggregate L2 BW
// (488MB / 37.5us = 13.0). Occupancy/VALU/prefetch/atomic changes never moved B bytes -> all
// null. R7's EBLK=64 failure had HALF the waves (1876, 4/block) + LDS-atomic reduce. v15:
// EBLK=64 with 512 threads -> 469 x 8 = 3752 waves (IDENTICAL to v8/v12), v12 two-phase
// exclusive-slab reduce, full-K per block (single-block atomics). B: 488 -> 244 MB.
__global__ __launch_bounds__(512, 2) void k_egemm(const u16* __restrict__ outB,
                                               const u16* __restrict__ a1b,
                                               const u16* __restrict__ B2b,
                                               const int* __restrict__ ei,
                                               float* __restrict__ agg){
  int tid = threadIdx.x;
  int l = tid & 63, w = tid >> 6;          // w in 0..7
  int m16 = l & 15, q = l >> 4;
  int eb = blockIdx.x * EBLK;

  __shared__ __align__(16) u16 a1l[EBLK*A1LS];       // 8448 B
  __shared__ __align__(16) float red[4][EBLK*RS];    // 67584 B

  // per-lane A-operand hoist: 4 edge tiles x 2 halves
  int nidx[4];
  #pragma unroll
  for(int t=0;t<4;t++){
    int e = eb + t*16 + m16;
    nidx[t] = (e < N_EDGES) ? ei[e] : 0;
  }
  uint4 oE[4], oO[4];
  #pragma unroll
  for(int t=0;t<4;t++){
    oE[t] = *(const uint4*)(outB + (size_t)nidx[t]*64 +      q*8);
    oO[t] = *(const uint4*)(outB + (size_t)nidx[t]*64 + 32 + q*8);
  }

  // stage a1 (64 edges x 33 dwords)
  for(int idx = tid; idx < EBLK*33; idx += 512){
    int r = idx / 33, c = idx - r*33;
    int e = eb + r;
    u32 v = (e < N_EDGES) ? ((const u32*)(a1b + (size_t)e*A1S))[c] : 0u;
    ((u32*)a1l)[r*33 + c] = v;
  }
  __syncthreads();

  facc4 acc[4][4];
  #pragma unroll
  for(int t=0;t<4;t++)
    #pragma unroll
    for(int nt=0;nt<4;nt++) acc[t][nt] = (facc4){0.f,0.f,0.f,0.f};

  // wave w handles k-pairs [ks, ke): chunks 2k (half0) and 2k+1 (half1)
  int ks = (w*65) >> 3, ke = ((w+1)*65) >> 3;   // 8,8,8,8,8,8,8,9
  const frag8* __restrict__ Bg = (const frag8*)B2b;

  frag8 bA[4], bB[4];
  #pragma unroll
  for(int nt=0;nt<4;nt++) bA[nt] = Bg[(size_t)(2*ks)*256 + nt*64 + l];

  for(int k = ks; k < ke; ++k){
    // prefetch odd chunk of this pair
    #pragma unroll
    for(int nt=0;nt<4;nt++) bB[nt] = Bg[(size_t)(2*k+1)*256 + nt*64 + l];

    u32 av[4];
    #pragma unroll
    for(int t=0;t<4;t++){
      u32 a = a1l[(t*16 + m16)*A1LS + k];
      av[t] = a | (a << 16);
    }

    // even chunk (half 0): 4 edge-tiles x 4 nt
    #pragma unroll
    for(int t=0;t<4;t++){
      frag8 a = pack4h(oE[t], av[t]);
      #pragma unroll
      for(int nt=0;nt<4;nt++)
        acc[t][nt] = __builtin_amdgcn_mfma_f32_16x16x32_f16(a, bA[nt], acc[t][nt], 0,0,0);
    }

    // prefetch even chunk of next pair
    int kn = (k+1 < ke) ? (k+1) : k;
    #pragma unroll
    for(int nt=0;nt<4;nt++) bA[nt] = Bg[(size_t)(2*kn)*256 + nt*64 + l];

    // odd chunk (half 1)
    #pragma unroll
    for(int t=0;t<4;t++){
      frag8 a = pack4h(oO[t], av[t]);
      #pragma unroll
      for(int nt=0;nt<4;nt++)
        acc[t][nt] = __builtin_amdgcn_mfma_f32_16x16x32_f16(a, bB[nt], acc[t][nt], 0,0,0);
    }
  }

  // two-phase exclusive-slab reduce (no LDS atomics):
  // waves 0-3 write slab w; barrier; waves 4-7 += into slab w-4; barrier.
  if(w < 4){
    #pragma unroll
    for(int t=0;t<4;t++)
      #pragma unroll
      for(int nt=0;nt<4;nt++)
        #pragma unroll
        for(int r=0;r<4;r++){
          int el = t*16 + q*4 + r;
          red[w][el*RS + nt*16 + m16] = acc[t][nt][r];
        }
  }
  __syncthreads();
  if(w >= 4){
    #pragma unroll
    for(int t=0;t<4;t++)
      #pragma unroll
      for(int nt=0;nt<4;nt++)
        #pragma unroll
        for(int r=0;r<4;r++){
          int el = t*16 + q*4 + r;
          red[w-4][el*RS + nt*16 + m16] += acc[t][nt][r];
        }
  }
  __syncthreads();

  // one global atomic per (edge, o) — single block touches each (edge,o)
  for(int i = tid; i < EBLK*64; i += 512){
    int el = i >> 6, o = i & 63;
    int e = eb + el;
    if(e < N_EDGES){
      float s = red[0][el*RS + o] + red[1][el*RS + o]
              + red[2][el*RS + o] + red[3][el*RS + o];
      atomicAdd(&agg[(size_t)ei[N_EDGES + e]*64 + o], s);
    }
  }
}

// ---------------- node update: MFMA GRU, fp16 split datapath (unchanged) ----------------
__global__ __launch_bounds__(256) void k_node(float* __restrict__ agg, const float* __restrict__ deg,
                                              float* __restrict__ outF, u16* __restrict__ outB,
                                              const u16* __restrict__ gBn, const float* __restrict__ convb,
                                              const float* __restrict__ bih, const float* __restrict__ bhh){
  int tid = threadIdx.x;
  int l = tid & 63, w = tid >> 6;
  int m16 = l & 15, q = l >> 4;
  int nb = blockIdx.x * 16;

  __shared__ __align__(16) u16 hhi[16][HS], hlo[16][HS];
  __shared__ __align__(16) u16 mhi[16][HS], mlo[16][HS];

  {
    float4 v = ((const float4*)(outF + (size_t)nb*64))[tid];
    int base = tid*4;
    int node = base >> 6, o = base & 63;
    float vv[4] = {v.x, v.y, v.z, v.w};
    #pragma unroll
    for(int t=0;t<4;t++){
      u16 hb = f2h(vv[t]);
      hhi[node][o+t] = hb;
      hlo[node][o+t] = f2h(vv[t] - h2f(hb));
    }
  }
  __syncthreads();

  const frag8* __restrict__ Bg = (const frag8*)gBn;

#define GEMM6(ACC, A0, A1, L0, L1, T)                                      \
  {                                                                        \
    const frag8* bp = Bg + (size_t)(T)*256 + l;                            \
    frag8 b0 = bp[0], b1 = bp[64], b2 = bp[128], b3 = bp[192];             \
    ACC = __builtin_amdgcn_mfma_f32_16x16x32_f16(A0, b0, ACC, 0,0,0);      \
    ACC = __builtin_amdgcn_mfma_f32_16x16x32_f16(A1, b1, ACC, 0,0,0);      \
    ACC = __builtin_amdgcn_mfma_f32_16x16x32_f16(L0, b0, ACC, 0,0,0);      \
    ACC = __builtin_amdgcn_mfma_f32_16x16x32_f16(L1, b1, ACC, 0,0,0);      \
    ACC = __builtin_amdgcn_mfma_f32_16x16x32_f16(A0, b2, ACC, 0,0,0);      \
    ACC = __builtin_amdgcn_mfma_f32_16x16x32_f16(A1, b3, ACC, 0,0,0);      \
  }

  frag8 hA0 = *(const frag8*)&hhi[m16][q*8];
  frag8 hA1 = *(const frag8*)&hhi[m16][32 + q*8];
  frag8 hL0 = *(const frag8*)&hlo[m16][q*8];
  frag8 hL1 = *(const frag8*)&hlo[m16][32 + q*8];

  facc4 dR  = (facc4){0.f,0.f,0.f,0.f};
  facc4 ghA = (facc4){0.f,0.f,0.f,0.f};
  facc4 ghB = (facc4){0.f,0.f,0.f,0.f};
  facc4 ghC = (facc4){0.f,0.f,0.f,0.f};
  GEMM6(dR,  hA0, hA1, hL0, hL1, w);
  GEMM6(ghA, hA0, hA1, hL0, hL1, 16 + w);
  GEMM6(ghB, hA0, hA1, hL0, hL1, 20 + w);
  GEMM6(ghC, hA0, hA1, hL0, hL1, 24 + w);

  int o = w*16 + m16;
  float cb = convb[o];
  #pragma unroll
  for(int r=0;r<4;r++){
    int node = q*4 + r;
    int n = nb + node;
    float a = agg[(size_t)n*64 + o] / fmaxf(deg[n], 1.0f) + dR[r] + cb;
    agg[(size_t)n*64 + o] = 0.f;
    float mv = lrelu(a);
    u16 mb = f2h(mv);
    mhi[node][o] = mb;
    mlo[node][o] = f2h(mv - h2f(mb));
  }
  __syncthreads();

  frag8 mA0 = *(const frag8*)&mhi[m16][q*8];
  frag8 mA1 = *(const frag8*)&mhi[m16][32 + q*8];
  frag8 mL0 = *(const frag8*)&mlo[m16][q*8];
  frag8 mL1 = *(const frag8*)&mlo[m16][32 + q*8];

  facc4 giA = (facc4){0.f,0.f,0.f,0.f};
  facc4 giB = (facc4){0.f,0.f,0.f,0.f};
  facc4 giC = (facc4){0.f,0.f,0.f,0.f};
  GEMM6(giA, mA0, mA1, mL0, mL1, 4 + w);
  GEMM6(giB, mA0, mA1, mL0, mL1, 8 + w);
  GEMM6(giC, mA0, mA1, mL0, mL1, 12 + w);
#undef GEMM6

  float bi0 = bih[o], bi1 = bih[64+o], bi2 = bih[128+o];
  float bh0 = bhh[o], bh1 = bhh[64+o], bh2 = bhh[128+o];
  #pragma unroll
  for(int r=0;r<4;r++){
    int node = q*4 + r;
    int n = nb + node;
    float ir = giA[r]+bi0, iz = giB[r]+bi1, inn = giC[r]+bi2;
    float hr = ghA[r]+bh0, hz = ghB[r]+bh1, hn = ghC[r]+bh2;
    float rr  = sigmoidf(ir + hr);
    float z   = sigmoidf(iz + hz);
    float ngv = tanhf(inn + rr*hn);
    float hold = h2f(hhi[node][o]) + h2f(hlo[node][o]);
    float hnew = (1.f - z)*ngv + z*hold;
    if(n < N_NODES){
      outF[(size_t)n*64 + o] = hnew;
      outB[(size_t)n*64 + o] = f2h(hnew);
    }
  }
}

// ---------------- stem head ----------------
__global__ __launch_bounds__(512) void k_stem(const float* __restrict__ outF, const int* __restrict__ sidx,
                                              const float4* __restrict__ s1P, const float* __restrict__ s1b,
                                              const float4* __restrict__ s2P, const float* __restrict__ s2b,
                                              void* __restrict__ dout, const int* __restrict__ flag){
  int grp = threadIdx.x >> 7, t = threadIdx.x & 127;
  int s = blockIdx.x*4 + grp;
  int isf = *flag;
  __shared__ __align__(16) float xs[4][64], hid[4][64];
  int a = sidx[s];
  if(t < 64) xs[grp][t] = outF[(size_t)a*64 + t];
  __syncthreads();
  if(t < 64){
    float acc = s1b[t];
    const float4* xp = (const float4*)xs[grp];
    #pragma unroll 8
    for(int j4=0;j4<16;j4++){
      float4 w = s1P[j4*64+t];
      float4 x = xp[j4];
      acc += w.x*x.x + w.y*x.y + w.z*x.z + w.w*x.w;
    }
    hid[grp][t] = lrelu(acc);
  }
  __syncthreads();
  if(t < 105){
    float acc = s2b[t];
    const float4* hp = (const float4*)hid[grp];
    #pragma unroll 8
    for(int j4=0;j4<16;j4++){
      float4 w = s2P[j4*112+t];
      float4 h = hp[j4];
      acc += w.x*h.x + w.y*h.y + w.z*h.z + w.w*h.w;
    }
    store_out(dout, isf, OUT_STEM + s*105 + t, acc);
  }
}

// ---------------- jbond head ----------------
__global__ __launch_bounds__(512) void k_jbond(const float* __restrict__ outF, const int* __restrict__ jidx,
                                               const float4* __restrict__ j1P, const float* __restrict__ j1b,
                                               const float* __restrict__ j2w, const float* __restrict__ j2b,
                                               void* __restrict__ dout, const int* __restrict__ flag){
  int grp = threadIdx.x >> 7, t = threadIdx.x & 127;
  int jb = blockIdx.x*4 + grp;
  int isf = *flag;
  __shared__ __align__(16) float xs[4][2][64], hid[4][2][64];
  int at = t >> 6, k = t & 63;
  int a = jidx[jb*2 + at];
  xs[grp][at][k] = outF[(size_t)a*64 + k];
  __syncthreads();
  {
    float acc = j1b[k];
    const float4* xp = (const float4*)xs[grp][at];
    #pragma unroll 8
    for(int j4=0;j4<16;j4++){
      float4 w = j1P[j4*64+k];
      float4 x = xp[j4];
      acc += w.x*x.x + w.y*x.y + w.z*x.z + w.w*x.w;
    }
    hid[grp][at][k] = lrelu(acc);
  }
  __syncthreads();
  if(t < 64){
    float p = (hid[grp][0][t] + hid[grp][1][t]) * j2w[t];
    #pragma unroll
    for(int s=32;s;s>>=1) p += __shfl_xor(p, s, 64);
    if(t==0) store_out(dout, isf, OUT_JB + jb, 0.5f*p + j2b[0]);
  }
}

// ---------------- Set2Set + final linear ----------------
__global__ __launch_bounds__(64) void k_s2s(const float* __restrict__ outF, const int* __restrict__ batch,
                                            const float* __restrict__ bih, const float* __restrict__ bhh,
                                            const float* __restrict__ loutw, const float* __restrict__ loutb,
                                            void* __restrict__ dout, const int* __restrict__ flag){
  int b = blockIdx.x, t = threadIdx.x;
  int isf = *flag;
  float i_ = bih[t]     + bhh[t];
  float g_ = bih[128+t] + bhh[128+t];
  float o_ = bih[192+t] + bhh[192+t];
  float c  = sigmoidf(i_)*tanhf(g_);
  float q  = sigmoidf(o_)*tanhf(c);

  int lo = lower_bound_i(batch, N_NODES, b);
  int hi = lower_bound_i(batch, N_NODES, b+1);

  float emax = -3.4e38f;
  for(int n=lo;n<hi;n++){
    float p = outF[n*64+t]*q;
    #pragma unroll
    for(int s=32;s;s>>=1) p += __shfl_xor(p, s, 64);
    emax = fmaxf(emax, p);
  }
  float Z = 0.f, racc = 0.f;
  for(int n=lo;n<hi;n++){
    float v = outF[n*64+t];
    float p = v*q;
    #pragma unroll
    for(int s=32;s;s>>=1) p += __shfl_xor(p, s, 64);
    float w = expf(p - emax);
    Z += w; racc += w*v;
  }
  float rp = (hi>lo) ? racc/Z : 0.f;

  #pragma unroll
  for(int j=0;j<2;j++){
    float p = q*loutw[j*128+t] + rp*loutw[j*128+64+t];
    #pragma unroll
    for(int s=32;s;s>>=1) p += __shfl_xor(p, s, 64);
    if(t==0) store_out(dout, isf, OUT_FINAL + b*2 + j, p + loutb[j]);
  }
}

extern "C" void kernel_launch(void* const* d_in, const int* in_sizes, int n_in,
                              void* d_out, int out_size, void* d_ws, size_t ws_size,
                              hipStream_t stream) {
  const int* edge_index  = (const int*)d_in[28];
  const int* stem_atmidx = (const int*)d_in[29];
  const int* jbond_atmidx= (const int*)d_in[30];
  const int* batch       = (const int*)d_in[31];

  char* ws = (char*)d_ws;
  size_t off = 0;
  auto alloc = [&](size_t bytes)->void*{ void* p = ws + off; off = (off + bytes + 255) & ~(size_t)255; return p; };

  int*   flag = (int*)  alloc(4);
  float* outF = (float*)alloc((size_t)PADN*64*4);
  u16*   outB = (u16*)  alloc((size_t)PADN*64*2);
  float* agg  = (float*)alloc((size_t)PADN*64*4);
  u16*   a1b  = (u16*)  alloc((size_t)N_EDGES*A1S*2);
  u16*   B2b  = (u16*)  alloc((size_t)KCH*2048*2 + 2048*2);   // +1 chunk slack for prefetch tail
  u16*   gBn  = (u16*)  alloc((size_t)NWTILES*4*512*2);       // node-GEMM weights (112 KB)
  float* deg  = (float*)alloc((size_t)PADN*4);
  float4* s1P   = (float4*)alloc(1024*16);
  float4* s2P   = (float4*)alloc(1792*16);
  float4* j1P   = (float4*)alloc(1024*16);

  static const int cvt_idx[N_CVT] = {0,1,2,3,4,5,6,7,8,9,10,11,12,13,14,15,16,17,18,19,20,21,24,25,26,27};
  CvtArgs A;
  float* cF[N_CVT];
  for(int i=0;i<N_CVT;i++){
    int src = cvt_idx[i];
    int n = in_sizes[src];
    cF[i] = (float*)alloc((size_t)n*4);
    A.src[i] = d_in[src];
    A.dst[i] = cF[i];
    A.n[i]   = n;
  }
  (void)ws_size; (void)n_in; (void)out_size;
  float* xF=cF[0];   float* eaF=cF[1];  float* l0w=cF[2];  float* l0b=cF[3];
  float* e1w=cF[4];  float* e1b=cF[5];  float* e2w=cF[6];  float* e2b=cF[7];
  float* rootw=cF[8];float* convb=cF[9];
  float* wih=cF[10]; float* whh=cF[11]; float* bih=cF[12]; float* bhh=cF[13];
  float* s1w=cF[14]; float* s1b=cF[15]; float* s2w=cF[16]; float* s2b=cF[17];
  float* j1w=cF[18]; float* j1b=cF[19]; float* j2w=cF[20]; float* j2b=cF[21];
  float* lbih=cF[22];float* lbhh=cF[23];float* loutw=cF[24];float* loutb=cF[25];

  hipMemsetAsync(flag, 0, 4, stream);

  k_sniff <<<128, 256, 0, stream>>>((const u16*)d_in[0], in_sizes[0], flag, deg, agg, outF, outB);
  k_cvt   <<<512, 256, 0, stream>>>(A, flag);

  k_lin0    <<<N_NODES, 64, 0, stream>>>(xF, l0w, l0b, outF, outB);
  k_a1      <<<N_EDGES, 128, 0, stream>>>(eaF, e1w, e1b, a1b, edge_index, deg);
  k_packAll <<<PACK_TOTAL/256, 256, 0, stream>>>(e2w, e2b, B2b, rootw, wih, whh, gBn,
                                                 s1w, s2w, j1w, s1P, s2P, j1P);

  for(int it=0; it<6; it++){
    k_egemm<<<EGRIDE, 512, 0, stream>>>(outB, a1b, B2b, edge_index, agg);
    k_node <<<NGROUPS, 256, 0, stream>>>(agg, deg, outF, outB, gBn, convb, bih, bhh);
  }

  k_stem <<<N_STEMS/4, 512, 0, stream>>>(outF, stem_atmidx, s1P, s1b, s2P, s2b, d_out, flag);
  k_jbond<<<N_JBONDS/4, 512, 0, stream>>>(outF, jbond_atmidx, j1P, j1b, j2w, j2b, d_out, flag);
  k_s2s  <<<NUM_GRAPHS, 64, 0, stream>>>(outF, batch, lbih, lbhh, loutw, loutb, d_out, flag);
}

// Round 13
// 431.979 us; speedup vs baseline: 1.1129x; 1.0115x over previous
//
#include <hip/hip_runtime.h>

typedef unsigned short u16;
typedef unsigned int   u32;

#define N_NODES    15000
#define PADN       15008
#define N_EDGES    30000
#define NUM_GRAPHS 600
#define N_STEMS    6000
#define N_JBONDS   3000

#define OUT_FINAL  0
#define OUT_STEM   1200
#define OUT_JB     631200

#define A1S 68                // a1b (global) row stride u16
#define N_CVT 26

// ---- edge-GEMM geometry (v16: v15 + LDS-deduplicated outB gather) ----
#define EBLK 64               // edges per block (4 MFMA tiles)
#define EGRIDE 469            // ceil(30000/64)
#define KCH 130               // K chunks of 32 (K = 65*64 = 4160)
#define A1LS 66               // a1l row stride u16
#define RS   66               // red row stride f32
#define O2W 10                // o2l row stride in uint4 (40 dwords: <=4-way on reads)

// ---- k_node (MFMA) geometry ----
#define NGROUPS (PADN/16)     // 938 groups of 16 nodes
#define NWTILES 28            // root 0-3, wih 4-15, whh 16-27
#define HS 72                 // LDS staging row stride u16

// ---- fused pack kernel segments ----
#define PACK_W2B_N (KCH*2048)        // 266240
#define PACK_NW_N  (NWTILES*4*512)   // 57344
#define PACK_HD_N  1792
#define PACK_TOTAL (PACK_W2B_N + PACK_NW_N + PACK_HD_N)   // 325376 = 1271*256

typedef short frag8 __attribute__((ext_vector_type(8)));   // 8 f16 (4 VGPRs)
typedef float facc4 __attribute__((ext_vector_type(4)));   // 4 f32 acc
typedef _Float16 h16x2 __attribute__((ext_vector_type(2)));

__device__ __forceinline__ float u2f(u16 v){ union{u32 i; float f;} c; c.i=((u32)v)<<16; return c.f; }
__device__ __forceinline__ u16  f2b(float f){ union{float f; u32 u;} c; c.f=f; u32 u=c.u;
                                              return (u16)((u + 0x7fffu + ((u>>16)&1u))>>16); }
__device__ __forceinline__ u16  f2h(float f){ union{_Float16 h; u16 u;} c; c.h = (_Float16)f; return c.u; }
__device__ __forceinline__ float h2f(u16 v){ union{u16 u; _Float16 h;} c; c.u = v; return (float)c.h; }
__device__ __forceinline__ float lrelu(float x){ return x>0.f ? x : 0.01f*x; }
__device__ __forceinline__ float sigmoidf(float x){ return 1.f/(1.f+expf(-x)); }

__device__ __forceinline__ int lower_bound_i(const int* __restrict__ a, int n, int v){
  int lo=0, hi=n;
  while(lo<hi){ int m=(lo+hi)>>1; if(a[m]<v) lo=m+1; else hi=m; }
  return lo;
}

__device__ __forceinline__ void store_out(void* dout, int isf, int idx, float v){
  if(isf) ((float*)dout)[idx] = v;
  else    ((u16*)dout)[idx]   = f2b(v);
}

// fp16 A-fragment: 4x v_pk_mul_f16
__device__ __forceinline__ frag8 pack4h(uint4 v, u32 av2){
  union { u32 d[4]; frag8 f; } au;
  h16x2 a; { union{u32 u; h16x2 h;} c; c.u = av2; a = c.h; }
  { union{u32 u; h16x2 h;} c; c.u = v.x; c.h = a * c.h; au.d[0] = c.u; }
  { union{u32 u; h16x2 h;} c; c.u = v.y; c.h = a * c.h; au.d[1] = c.u; }
  { union{u32 u; h16x2 h;} c; c.u = v.z; c.h = a * c.h; au.d[2] = c.u; }
  { union{u32 u; h16x2 h;} c; c.u = v.w; c.h = a * c.h; au.d[3] = c.u; }
  return au.f;
}

// ---------------- dtype sniff + workspace zero-init ----------------
__global__ __launch_bounds__(256) void k_sniff(const u16* __restrict__ x, int n, int* __restrict__ flag,
                                               float* __restrict__ deg, float* __restrict__ agg,
                                               float* __restrict__ outF, u16* __restrict__ outB){
  int tid = blockIdx.x*256 + threadIdx.x;
  int stride = gridDim.x*256;
  int local = 0;
  for(int i = tid; i < n; i += stride){
    u16 v = x[i];
    if(((v>>7)&0xFFu) == 0xFFu) local = 1;
  }
  if(local) atomicOr(flag, 1);
  float4 z = (float4){0.f,0.f,0.f,0.f};
  for(int i = tid; i < PADN; i += stride) deg[i] = 0.f;
  for(int i = tid; i < PADN*64/4; i += stride) ((float4*)agg)[i] = z;
  for(int i = tid; i < (PADN-N_NODES)*64/4; i += stride) ((float4*)(outF + (size_t)N_NODES*64))[i] = z;
  for(int i = tid; i < (PADN-N_NODES)*64/8; i += stride) ((float4*)(outB + (size_t)N_NODES*64))[i] = z;
}

// ---------------- convert float inputs to f32 ----------------
struct CvtArgs { const void* src[N_CVT]; float* dst[N_CVT]; int n[N_CVT]; };

__global__ __launch_bounds__(256) void k_cvt(CvtArgs A, const int* __restrict__ flag){
  int isf = *flag;
  int tid = blockIdx.x*256 + threadIdx.x;
  int stride = gridDim.x*256;
  for(int b=0; b<N_CVT; b++){
    int n = A.n[b];
    const float* sf = (const float*)A.src[b];
    const u16*   sb = (const u16*)A.src[b];
    float* d = A.dst[b];
    for(int i=tid; i<n; i+=stride) d[i] = isf ? sf[i] : u2f(sb[i]);
  }
}

// ---------------- lin0 (writes f32 out + fp16 mirror) ----------------
__global__ __launch_bounds__(64) void k_lin0(const float* __restrict__ x, const float* __restrict__ w,
                                             const float* __restrict__ b,
                                             float* __restrict__ outF, u16* __restrict__ outB){
  int n = blockIdx.x, o = threadIdx.x;
  __shared__ float xs[14];
  if(o<14) xs[o] = x[n*14+o];
  __syncthreads();
  float acc = b[o];
  #pragma unroll
  for(int i=0;i<14;i++) acc += xs[i]*w[o*14+i];
  float v = lrelu(acc);
  outF[n*64+o] = v;
  outB[n*64+o] = f2h(v);
}

// ---------------- a1b fp16 (+ folded deg atomic on thread k==65) ----------------
__global__ __launch_bounds__(128) void k_a1(const float* __restrict__ ea,
                                            const float* __restrict__ en1w, const float* __restrict__ en1b,
                                            u16* __restrict__ a1b,
                                            const int* __restrict__ ei, float* __restrict__ deg){
  int e = blockIdx.x, k = threadIdx.x;
  if(k >= A1S) return;
  float v = 0.f;
  if(k < 64){
    float acc = en1b[k];
    #pragma unroll
    for(int c=0;c<4;c++) acc += ea[e*4+c] * en1w[k*4+c];
    v = lrelu(acc);
  } else if(k == 64) v = 1.0f;
  a1b[e*A1S + k] = f2h(v);
  if(k == 65) atomicAdd(&deg[ei[N_EDGES + e]], 1.0f);
}

// ---------------- fused weight-pack kernel (W2b + NodeW + Heads), fp16 ----------------
__global__ __launch_bounds__(256) void k_packAll(const float* __restrict__ en2w, const float* __restrict__ en2b,
                                                 u16* __restrict__ B2b,
                                                 const float* __restrict__ rootw, const float* __restrict__ wih,
                                                 const float* __restrict__ whh, u16* __restrict__ gBn,
                                                 const float* __restrict__ s1w, const float* __restrict__ s2w,
                                                 const float* __restrict__ j1w,
                                                 float4* __restrict__ s1P, float4* __restrict__ s2P,
                                                 float4* __restrict__ j1P){
  int idx = blockIdx.x*256 + threadIdx.x;
  if(idx < PACK_W2B_N){
    int jj  = idx & 7;
    int l   = (idx >> 3) & 63;
    int nt  = (idx >> 9) & 3;
    int c   = idx >> 11;
    int q = l >> 4, m16 = l & 15;
    int kidx = c*32 + q*8 + jj;
    int k = kidx >> 6, j = kidx & 63;
    int o = nt*16 + m16;
    float v = (k < 64) ? en2w[((size_t)(j*64 + o))*64 + k] : en2b[j*64 + o];
    B2b[idx] = f2h(v);
    return;
  }
  idx -= PACK_W2B_N;
  if(idx < PACK_NW_N){
    int jj = idx & 7, l = (idx>>3) & 63, ch = (idx>>9) & 3, t = idx >> 11;
    int m16 = l & 15, q = l >> 4;
    int j = ((ch & 1) ? 32 : 0) + q*8 + jj;
    float v;
    if(t < 4){        int o = t*16 + m16;        v = rootw[j*64 + o]; }
    else if(t < 16){  int g = (t-4)*16 + m16;    v = wih[(size_t)g*64 + j]; }
    else {            int g = (t-16)*16 + m16;   v = whh[(size_t)g*64 + j]; }
    u16 hb = f2h(v);
    gBn[idx] = (ch >> 1) ? f2h(v - h2f(hb)) : hb;
    return;
  }
  idx -= PACK_NW_N;
  if(idx < PACK_HD_N){
    if(idx < 1024){
      int o = idx & 63, j4 = idx >> 6;
      const float* r = s1w + o*64 + 4*j4;
      s1P[idx] = (float4){r[0], r[1], r[2], r[3]};
      const float* r2 = j1w + o*64 + 4*j4;
      j1P[idx] = (float4){r2[0], r2[1], r2[2], r2[3]};
    }
    {
      int j4 = idx / 112, t = idx % 112;
      float4 v = {0.f,0.f,0.f,0.f};
      if(t < 105){
        const float* r = s2w + t*64 + 4*j4;
        v = (float4){r[0], r[1], r[2], r[3]};
      }
      s2P[idx] = v;
    }
  }
}

// ---------------- edge-GEMM v16: v15 + LDS-deduplicated outB gather ----------------
// R12 post-mortem: v15 (B bytes /2) gave only -10% -> B-BW model incomplete. Audit found
// the invariant across v8-v15: ALL 8 waves redundantly issue the same per-lane outB
// gathers -> 1.9M random 16B global requests/dispatch (8x the 240k unique). That term
// matches every null (R6/R9/R10/R11 never changed it). v16: cooperative gather, one 16B
// request per (edge,part), staged in LDS (aliased over `red`, used disjointly in time;
// extra barrier separates), then per-thread VGPR hoist from LDS. K-loop unchanged.
__global__ __launch_bounds__(512, 2) void k_egemm(const u16* __restrict__ outB,
                                               const u16* __restrict__ a1b,
                                               const u16* __restrict__ B2b,
                                               const int* __restrict__ ei,
                                               float* __restrict__ agg){
  int tid = threadIdx.x;
  int l = tid & 63, w = tid >> 6;          // w in 0..7
  int m16 = l & 15, q = l >> 4;
  int eb = blockIdx.x * EBLK;

  __shared__ __align__(16) u16 a1l[EBLK*A1LS];       // 8448 B
  __shared__ __align__(16) float red[4][EBLK*RS];    // 67584 B (aliased as o2l in prologue)
  uint4* o2l = (uint4*)&red[0][0];                   // [EBLK][O2W], 10240 B

  // cooperative outB gather: exactly one 16B request per (edge, part)
  for(int i = tid; i < EBLK*8; i += 512){
    int el = i >> 3, part = i & 7;
    int e = eb + el;
    int node = (e < N_EDGES) ? ei[e] : 0;
    o2l[el*O2W + part] = *(const uint4*)(outB + (size_t)node*64 + part*8);
  }
  // stage a1 (64 edges x 33 dwords)
  for(int idx = tid; idx < EBLK*33; idx += 512){
    int r = idx / 33, c = idx - r*33;
    int e = eb + r;
    u32 v = (e < N_EDGES) ? ((const u32*)(a1b + (size_t)e*A1S))[c] : 0u;
    ((u32*)a1l)[r*33 + c] = v;
  }
  __syncthreads();

  // per-thread A-operand hoist from LDS (row el: part q -> E half, part 4+q -> O half)
  uint4 oE[4], oO[4];
  #pragma unroll
  for(int t=0;t<4;t++){
    int el = t*16 + m16;
    oE[t] = o2l[el*O2W + q];
    oO[t] = o2l[el*O2W + 4 + q];
  }
  __syncthreads();   // o2l dead from here; red may now be written

  facc4 acc[4][4];
  #pragma unroll
  for(int t=0;t<4;t++)
    #pragma unroll
    for(int nt=0;nt<4;nt++) acc[t][nt] = (facc4){0.f,0.f,0.f,0.f};

  // wave w handles k-pairs [ks, ke): chunks 2k (half0) and 2k+1 (half1)
  int ks = (w*65) >> 3, ke = ((w+1)*65) >> 3;   // 8,8,8,8,8,8,8,9
  const frag8* __restrict__ Bg = (const frag8*)B2b;

  frag8 bA[4], bB[4];
  #pragma unroll
  for(int nt=0;nt<4;nt++) bA[nt] = Bg[(size_t)(2*ks)*256 + nt*64 + l];

  for(int k = ks; k < ke; ++k){
    // prefetch odd chunk of this pair
    #pragma unroll
    for(int nt=0;nt<4;nt++) bB[nt] = Bg[(size_t)(2*k+1)*256 + nt*64 + l];

    u32 av[4];
    #pragma unroll
    for(int t=0;t<4;t++){
      u32 a = a1l[(t*16 + m16)*A1LS + k];
      av[t] = a | (a << 16);
    }

    // even chunk (half 0): 4 edge-tiles x 4 nt
    #pragma unroll
    for(int t=0;t<4;t++){
      frag8 a = pack4h(oE[t], av[t]);
      #pragma unroll
      for(int nt=0;nt<4;nt++)
        acc[t][nt] = __builtin_amdgcn_mfma_f32_16x16x32_f16(a, bA[nt], acc[t][nt], 0,0,0);
    }

    // prefetch even chunk of next pair
    int kn = (k+1 < ke) ? (k+1) : k;
    #pragma unroll
    for(int nt=0;nt<4;nt++) bA[nt] = Bg[(size_t)(2*kn)*256 + nt*64 + l];

    // odd chunk (half 1)
    #pragma unroll
    for(int t=0;t<4;t++){
      frag8 a = pack4h(oO[t], av[t]);
      #pragma unroll
      for(int nt=0;nt<4;nt++)
        acc[t][nt] = __builtin_amdgcn_mfma_f32_16x16x32_f16(a, bB[nt], acc[t][nt], 0,0,0);
    }
  }

  // two-phase exclusive-slab reduce (no LDS atomics)
  if(w < 4){
    #pragma unroll
    for(int t=0;t<4;t++)
      #pragma unroll
      for(int nt=0;nt<4;nt++)
        #pragma unroll
        for(int r=0;r<4;r++){
          int el = t*16 + q*4 + r;
          red[w][el*RS + nt*16 + m16] = acc[t][nt][r];
        }
  }
  __syncthreads();
  if(w >= 4){
    #pragma unroll
    for(int t=0;t<4;t++)
      #pragma unroll
      for(int nt=0;nt<4;nt++)
        #pragma unroll
        for(int r=0;r<4;r++){
          int el = t*16 + q*4 + r;
          red[w-4][el*RS + nt*16 + m16] += acc[t][nt][r];
        }
  }
  __syncthreads();

  // one global atomic per (edge, o) — single block touches each (edge,o)
  for(int i = tid; i < EBLK*64; i += 512){
    int el = i >> 6, o = i & 63;
    int e = eb + el;
    if(e < N_EDGES){
      float s = red[0][el*RS + o] + red[1][el*RS + o]
              + red[2][el*RS + o] + red[3][el*RS + o];
      atomicAdd(&agg[(size_t)ei[N_EDGES + e]*64 + o], s);
    }
  }
}

// ---------------- node update: MFMA GRU, fp16 split datapath (unchanged) ----------------
__global__ __launch_bounds__(256) void k_node(float* __restrict__ agg, const float* __restrict__ deg,
                                              float* __restrict__ outF, u16* __restrict__ outB,
                                              const u16* __restrict__ gBn, const float* __restrict__ convb,
                                              const float* __restrict__ bih, const float* __restrict__ bhh){
  int tid = threadIdx.x;
  int l = tid & 63, w = tid >> 6;
  int m16 = l & 15, q = l >> 4;
  int nb = blockIdx.x * 16;

  __shared__ __align__(16) u16 hhi[16][HS], hlo[16][HS];
  __shared__ __align__(16) u16 mhi[16][HS], mlo[16][HS];

  {
    float4 v = ((const float4*)(outF + (size_t)nb*64))[tid];
    int base = tid*4;
    int node = base >> 6, o = base & 63;
    float vv[4] = {v.x, v.y, v.z, v.w};
    #pragma unroll
    for(int t=0;t<4;t++){
      u16 hb = f2h(vv[t]);
      hhi[node][o+t] = hb;
      hlo[node][o+t] = f2h(vv[t] - h2f(hb));
    }
  }
  __syncthreads();

  const frag8* __restrict__ Bg = (const frag8*)gBn;

#define GEMM6(ACC, A0, A1, L0, L1, T)                                      \
  {                                                                        \
    const frag8* bp = Bg + (size_t)(T)*256 + l;                            \
    frag8 b0 = bp[0], b1 = bp[64], b2 = bp[128], b3 = bp[192];             \
    ACC = __builtin_amdgcn_mfma_f32_16x16x32_f16(A0, b0, ACC, 0,0,0);      \
    ACC = __builtin_amdgcn_mfma_f32_16x16x32_f16(A1, b1, ACC, 0,0,0);      \
    ACC = __builtin_amdgcn_mfma_f32_16x16x32_f16(L0, b0, ACC, 0,0,0);      \
    ACC = __builtin_amdgcn_mfma_f32_16x16x32_f16(L1, b1, ACC, 0,0,0);      \
    ACC = __builtin_amdgcn_mfma_f32_16x16x32_f16(A0, b2, ACC, 0,0,0);      \
    ACC = __builtin_amdgcn_mfma_f32_16x16x32_f16(A1, b3, ACC, 0,0,0);      \
  }

  frag8 hA0 = *(const frag8*)&hhi[m16][q*8];
  frag8 hA1 = *(const frag8*)&hhi[m16][32 + q*8];
  frag8 hL0 = *(const frag8*)&hlo[m16][q*8];
  frag8 hL1 = *(const frag8*)&hlo[m16][32 + q*8];

  facc4 dR  = (facc4){0.f,0.f,0.f,0.f};
  facc4 ghA = (facc4){0.f,0.f,0.f,0.f};
  facc4 ghB = (facc4){0.f,0.f,0.f,0.f};
  facc4 ghC = (facc4){0.f,0.f,0.f,0.f};
  GEMM6(dR,  hA0, hA1, hL0, hL1, w);
  GEMM6(ghA, hA0, hA1, hL0, hL1, 16 + w);
  GEMM6(ghB, hA0, hA1, hL0, hL1, 20 + w);
  GEMM6(ghC, hA0, hA1, hL0, hL1, 24 + w);

  int o = w*16 + m16;
  float cb = convb[o];
  #pragma unroll
  for(int r=0;r<4;r++){
    int node = q*4 + r;
    int n = nb + node;
    float a = agg[(size_t)n*64 + o] / fmaxf(deg[n], 1.0f) + dR[r] + cb;
    agg[(size_t)n*64 + o] = 0.f;
    float mv = lrelu(a);
    u16 mb = f2h(mv);
    mhi[node][o] = mb;
    mlo[node][o] = f2h(mv - h2f(mb));
  }
  __syncthreads();

  frag8 mA0 = *(const frag8*)&mhi[m16][q*8];
  frag8 mA1 = *(const frag8*)&mhi[m16][32 + q*8];
  frag8 mL0 = *(const frag8*)&mlo[m16][q*8];
  frag8 mL1 = *(const frag8*)&mlo[m16][32 + q*8];

  facc4 giA = (facc4){0.f,0.f,0.f,0.f};
  facc4 giB = (facc4){0.f,0.f,0.f,0.f};
  facc4 giC = (facc4){0.f,0.f,0.f,0.f};
  GEMM6(giA, mA0, mA1, mL0, mL1, 4 + w);
  GEMM6(giB, mA0, mA1, mL0, mL1, 8 + w);
  GEMM6(giC, mA0, mA1, mL0, mL1, 12 + w);
#undef GEMM6

  float bi0 = bih[o], bi1 = bih[64+o], bi2 = bih[128+o];
  float bh0 = bhh[o], bh1 = bhh[64+o], bh2 = bhh[128+o];
  #pragma unroll
  for(int r=0;r<4;r++){
    int node = q*4 + r;
    int n = nb + node;
    float ir = giA[r]+bi0, iz = giB[r]+bi1, inn = giC[r]+bi2;
    float hr = ghA[r]+bh0, hz = ghB[r]+bh1, hn = ghC[r]+bh2;
    float rr  = sigmoidf(ir + hr);
    float z   = sigmoidf(iz + hz);
    float ngv = tanhf(inn + rr*hn);
    float hold = h2f(hhi[node][o]) + h2f(hlo[node][o]);
    float hnew = (1.f - z)*ngv + z*hold;
    if(n < N_NODES){
      outF[(size_t)n*64 + o] = hnew;
      outB[(size_t)n*64 + o] = f2h(hnew);
    }
  }
}

// ---------------- stem head ----------------
__global__ __launch_bounds__(512) void k_stem(const float* __restrict__ outF, const int* __restrict__ sidx,
                                              const float4* __restrict__ s1P, const float* __restrict__ s1b,
                                              const float4* __restrict__ s2P, const float* __restrict__ s2b,
                                              void* __restrict__ dout, const int* __restrict__ flag){
  int grp = threadIdx.x >> 7, t = threadIdx.x & 127;
  int s = blockIdx.x*4 + grp;
  int isf = *flag;
  __shared__ __align__(16) float xs[4][64], hid[4][64];
  int a = sidx[s];
  if(t < 64) xs[grp][t] = outF[(size_t)a*64 + t];
  __syncthreads();
  if(t < 64){
    float acc = s1b[t];
    const float4* xp = (const float4*)xs[grp];
    #pragma unroll 8
    for(int j4=0;j4<16;j4++){
      float4 w = s1P[j4*64+t];
      float4 x = xp[j4];
      acc += w.x*x.x + w.y*x.y + w.z*x.z + w.w*x.w;
    }
    hid[grp][t] = lrelu(acc);
  }
  __syncthreads();
  if(t < 105){
    float acc = s2b[t];
    const float4* hp = (const float4*)hid[grp];
    #pragma unroll 8
    for(int j4=0;j4<16;j4++){
      float4 w = s2P[j4*112+t];
      float4 h = hp[j4];
      acc += w.x*h.x + w.y*h.y + w.z*h.z + w.w*h.w;
    }
    store_out(dout, isf, OUT_STEM + s*105 + t, acc);
  }
}

// ---------------- jbond head ----------------
__global__ __launch_bounds__(512) void k_jbond(const float* __restrict__ outF, const int* __restrict__ jidx,
                                               const float4* __restrict__ j1P, const float* __restrict__ j1b,
                                               const float* __restrict__ j2w, const float* __restrict__ j2b,
                                               void* __restrict__ dout, const int* __restrict__ flag){
  int grp = threadIdx.x >> 7, t = threadIdx.x & 127;
  int jb = blockIdx.x*4 + grp;
  int isf = *flag;
  __shared__ __align__(16) float xs[4][2][64], hid[4][2][64];
  int at = t >> 6, k = t & 63;
  int a = jidx[jb*2 + at];
  xs[grp][at][k] = outF[(size_t)a*64 + k];
  __syncthreads();
  {
    float acc = j1b[k];
    const float4* xp = (const float4*)xs[grp][at];
    #pragma unroll 8
    for(int j4=0;j4<16;j4++){
      float4 w = j1P[j4*64+k];
      float4 x = xp[j4];
      acc += w.x*x.x + w.y*x.y + w.z*x.z + w.w*x.w;
    }
    hid[grp][at][k] = lrelu(acc);
  }
  __syncthreads();
  if(t < 64){
    float p = (hid[grp][0][t] + hid[grp][1][t]) * j2w[t];
    #pragma unroll
    for(int s=32;s;s>>=1) p += __shfl_xor(p, s, 64);
    if(t==0) store_out(dout, isf, OUT_JB + jb, 0.5f*p + j2b[0]);
  }
}

// ---------------- Set2Set + final linear ----------------
__global__ __launch_bounds__(64) void k_s2s(const float* __restrict__ outF, const int* __restrict__ batch,
                                            const float* __restrict__ bih, const float* __restrict__ bhh,
                                            const float* __restrict__ loutw, const float* __restrict__ loutb,
                                            void* __restrict__ dout, const int* __restrict__ flag){
  int b = blockIdx.x, t = threadIdx.x;
  int isf = *flag;
  float i_ = bih[t]     + bhh[t];
  float g_ = bih[128+t] + bhh[128+t];
  float o_ = bih[192+t] + bhh[192+t];
  float c  = sigmoidf(i_)*tanhf(g_);
  float q  = sigmoidf(o_)*tanhf(c);

  int lo = lower_bound_i(batch, N_NODES, b);
  int hi = lower_bound_i(batch, N_NODES, b+1);

  float emax = -3.4e38f;
  for(int n=lo;n<hi;n++){
    float p = outF[n*64+t]*q;
    #pragma unroll
    for(int s=32;s;s>>=1) p += __shfl_xor(p, s, 64);
    emax = fmaxf(emax, p);
  }
  float Z = 0.f, racc = 0.f;
  for(int n=lo;n<hi;n++){
    float v = outF[n*64+t];
    float p = v*q;
    #pragma unroll
    for(int s=32;s;s>>=1) p += __shfl_xor(p, s, 64);
    float w = expf(p - emax);
    Z += w; racc += w*v;
  }
  float rp = (hi>lo) ? racc/Z : 0.f;

  #pragma unroll
  for(int j=0;j<2;j++){
    float p = q*loutw[j*128+t] + rp*loutw[j*128+64+t];
    #pragma unroll
    for(int s=32;s;s>>=1) p += __shfl_xor(p, s, 64);
    if(t==0) store_out(dout, isf, OUT_FINAL + b*2 + j, p + loutb[j]);
  }
}

extern "C" void kernel_launch(void* const* d_in, const int* in_sizes, int n_in,
                              void* d_out, int out_size, void* d_ws, size_t ws_size,
                              hipStream_t stream) {
  const int* edge_index  = (const int*)d_in[28];
  const int* stem_atmidx = (const int*)d_in[29];
  const int* jbond_atmidx= (const int*)d_in[30];
  const int* batch       = (const int*)d_in[31];

  char* ws = (char*)d_ws;
  size_t off = 0;
  auto alloc = [&](size_t bytes)->void*{ void* p = ws + off; off = (off + bytes + 255) & ~(size_t)255; return p; };

  int*   flag = (int*)  alloc(4);
  float* outF = (float*)alloc((size_t)PADN*64*4);
  u16*   outB = (u16*)  alloc((size_t)PADN*64*2);
  float* agg  = (float*)alloc((size_t)PADN*64*4);
  u16*   a1b  = (u16*)  alloc((size_t)N_EDGES*A1S*2);
  u16*   B2b  = (u16*)  alloc((size_t)KCH*2048*2 + 2048*2);   // +1 chunk slack for prefetch tail
  u16*   gBn  = (u16*)  alloc((size_t)NWTILES*4*512*2);       // node-GEMM weights (112 KB)
  float* deg  = (float*)alloc((size_t)PADN*4);
  float4* s1P   = (float4*)alloc(1024*16);
  float4* s2P   = (float4*)alloc(1792*16);
  float4* j1P   = (float4*)alloc(1024*16);

  static const int cvt_idx[N_CVT] = {0,1,2,3,4,5,6,7,8,9,10,11,12,13,14,15,16,17,18,19,20,21,24,25,26,27};
  CvtArgs A;
  float* cF[N_CVT];
  for(int i=0;i<N_CVT;i++){
    int src = cvt_idx[i];
    int n = in_sizes[src];
    cF[i] = (float*)alloc((size_t)n*4);
    A.src[i] = d_in[src];
    A.dst[i] = cF[i];
    A.n[i]   = n;
  }
  (void)ws_size; (void)n_in; (void)out_size;
  float* xF=cF[0];   float* eaF=cF[1];  float* l0w=cF[2];  float* l0b=cF[3];
  float* e1w=cF[4];  float* e1b=cF[5];  float* e2w=cF[6];  float* e2b=cF[7];
  float* rootw=cF[8];float* convb=cF[9];
  float* wih=cF[10]; float* whh=cF[11]; float* bih=cF[12]; float* bhh=cF[13];
  float* s1w=cF[14]; float* s1b=cF[15]; float* s2w=cF[16]; float* s2b=cF[17];
  float* j1w=cF[18]; float* j1b=cF[19]; float* j2w=cF[20]; float* j2b=cF[21];
  float* lbih=cF[22];float* lbhh=cF[23];float* loutw=cF[24];float* loutb=cF[25];

  hipMemsetAsync(flag, 0, 4, stream);

  k_sniff <<<128, 256, 0, stream>>>((const u16*)d_in[0], in_sizes[0], flag, deg, agg, outF, outB);
  k_cvt   <<<512, 256, 0, stream>>>(A, flag);

  k_lin0    <<<N_NODES, 64, 0, stream>>>(xF, l0w, l0b, outF, outB);
  k_a1      <<<N_EDGES, 128, 0, stream>>>(eaF, e1w, e1b, a1b, edge_index, deg);
  k_packAll <<<PACK_TOTAL/256, 256, 0, stream>>>(e2w, e2b, B2b, rootw, wih, whh, gBn,
                                                 s1w, s2w, j1w, s1P, s2P, j1P);

  for(int it=0; it<6; it++){
    k_egemm<<<EGRIDE, 512, 0, stream>>>(outB, a1b, B2b, edge_index, agg);
    k_node <<<NGROUPS, 256, 0, stream>>>(agg, deg, outF, outB, gBn, convb, bih, bhh);
  }

  k_stem <<<N_STEMS/4, 512, 0, stream>>>(outF, stem_atmidx, s1P, s1b, s2P, s2b, d_out, flag);
  k_jbond<<<N_JBONDS/4, 512, 0, stream>>>(outF, jbond_atmidx, j1P, j1b, j2w, j2b, d_out, flag);
  k_s2s  <<<NUM_GRAPHS, 64, 0, stream>>>(outF, batch, lbih, lbhh, loutw, loutb, d_out, flag);
}